// Round 1
// baseline (40.180 us; speedup 1.0000x reference)
//
#include <hip/hip_runtime.h>

#define USER_NUM 100000
#define ITEM_NUM 50000
#define HIDDEN   64
#define BATCH    16384
#define KNB      50

// fast, numerically stable log-sigmoid: min(x,0) - log(1 + exp(-|x|))
__device__ __forceinline__ float log_sigmoid(float x) {
    return fminf(x, 0.0f) - __logf(1.0f + __expf(-fabsf(x)));
}

__device__ __forceinline__ float dot4(float4 a, float4 b) {
    return a.x * b.x + a.y * b.y + a.z * b.z + a.w * b.w;
}

// butterfly sum over the 16-lane group (masks 1,2,4,8 stay within group)
__device__ __forceinline__ float red16(float v) {
    v += __shfl_xor(v, 1);
    v += __shfl_xor(v, 2);
    v += __shfl_xor(v, 4);
    v += __shfl_xor(v, 8);
    return v;
}

__global__ __launch_bounds__(256) void ultragcn_main(
    const int*   __restrict__ user,
    const int*   __restrict__ pos,
    const int*   __restrict__ neg,
    const float* __restrict__ pos_beta,
    const float* __restrict__ neg_beta,
    const float* __restrict__ weights,
    const int*   __restrict__ neighbor,
    const float* __restrict__ embs,
    float*       __restrict__ partial)
{
    const int tid  = threadIdx.x;
    const int wave = tid >> 6;       // 0..3
    const int lane = tid & 63;
    const int i    = blockIdx.x * 4 + wave;   // batch element (BATCH = 4096*4 exact)

    const int g  = lane >> 4;        // group 0..3 within wave
    const int gl = lane & 15;        // lane within group (one float4 of the 64-dim row)

    const int u = user[i];
    const int p = pos[i];
    const int n = neg[i];

    const float4* embs4 = (const float4*)embs;   // 16 float4 per row

    const float4 u4 = embs4[(long long)u * 16 + gl];
    const float4 p4 = embs4[(long long)p * 16 + gl];
    const float4 n4 = embs4[(long long)n * 16 + gl];

    // all 4 groups compute the same value (redundant but cheap: loads broadcast from cache)
    const float pos_logit = red16(dot4(u4, p4));
    const float neg_logit = red16(dot4(u4, n4));

    const int item = p - USER_NUM;

    // preload neighbor ids + weights into lanes 0..49
    int   nbv = 0;
    float wv  = 0.0f;
    if (lane < KNB) {
        nbv = neighbor[item * KNB + lane];
        wv  = weights[item * KNB + lane];
    }

    // neighbors 4-at-a-time: group g handles k = 4*t + g.
    // For k >= 50 (t=12, g=2,3): nbv/wv broadcast from lanes 50/51 which hold
    // {0, 0.0f} -> valid dummy load of row 0, weight 0 -> contributes nothing.
    float li = 0.0f;
#pragma unroll
    for (int t = 0; t < 13; ++t) {
        const int   k  = 4 * t + g;
        const int   nb = __shfl(nbv, k);
        const float w  = __shfl(wv,  k);
        const float4 e4 = embs4[(long long)nb * 16 + gl];
        const float d   = red16(dot4(u4, e4));
        li += -log_sigmoid(d) * w;
    }
    // each group's 16 lanes hold the group's partial; sum the 4 groups
    li += __shfl_xor(li, 16);
    li += __shfl_xor(li, 32);

    // LO + LC folded: -(1+pb)*ls(pos) - (1+nb)*ls(-neg)
    const float pb = pos_beta[i];
    const float nb = neg_beta[i];
    const float contrib = 2.5f * li
                        - (1.0f + pb) * log_sigmoid(pos_logit)
                        - (1.0f + nb) * log_sigmoid(-neg_logit);

    // block reduction across the 4 waves (all lanes of a wave hold contrib)
    __shared__ float s[4];
    if (lane == 0) s[wave] = contrib;
    __syncthreads();
    if (tid == 0) {
        partial[blockIdx.x] = s[0] + s[1] + s[2] + s[3];
    }
}

__global__ __launch_bounds__(256) void ultragcn_reduce(
    const float* __restrict__ partial, float* __restrict__ out, int n)
{
    const int tid  = threadIdx.x;
    const int lane = tid & 63;
    const int wave = tid >> 6;

    float s = 0.0f;
    for (int idx = tid; idx < n; idx += 256) s += partial[idx];

    // wave butterfly
    s += __shfl_xor(s, 1);
    s += __shfl_xor(s, 2);
    s += __shfl_xor(s, 4);
    s += __shfl_xor(s, 8);
    s += __shfl_xor(s, 16);
    s += __shfl_xor(s, 32);

    __shared__ float ws[4];
    if (lane == 0) ws[wave] = s;
    __syncthreads();
    if (tid == 0) out[0] = ws[0] + ws[1] + ws[2] + ws[3];
}

extern "C" void kernel_launch(void* const* d_in, const int* in_sizes, int n_in,
                              void* d_out, int out_size, void* d_ws, size_t ws_size,
                              hipStream_t stream)
{
    const int*   user     = (const int*)  d_in[0];
    const int*   pos      = (const int*)  d_in[1];
    const int*   neg      = (const int*)  d_in[2];
    const float* pos_beta = (const float*)d_in[3];
    const float* neg_beta = (const float*)d_in[4];
    const float* weights  = (const float*)d_in[5];
    const int*   neighbor = (const int*)  d_in[6];
    const float* embs     = (const float*)d_in[7];

    float* out     = (float*)d_out;
    float* partial = (float*)d_ws;       // 4096 floats = 16 KB scratch

    const int nblocks = BATCH / 4;       // 4096
    ultragcn_main<<<nblocks, 256, 0, stream>>>(
        user, pos, neg, pos_beta, neg_beta, weights, neighbor, embs, partial);
    ultragcn_reduce<<<1, 256, 0, stream>>>(partial, out, nblocks);
}

// Round 2
// 36.780 us; speedup vs baseline: 1.0924x; 1.0924x over previous
//
#include <hip/hip_runtime.h>

#define USER_NUM 100000
#define ITEM_NUM 50000
#define HIDDEN   64
#define BATCH    16384
#define KNB      50

// fast, numerically stable log-sigmoid: min(x,0) - log(1 + exp(-|x|))
__device__ __forceinline__ float log_sigmoid(float x) {
    return fminf(x, 0.0f) - __logf(1.0f + __expf(-fabsf(x)));
}

__device__ __forceinline__ float dot4(float4 a, float4 b) {
    return a.x * b.x + a.y * b.y + a.z * b.z + a.w * b.w;
}

// butterfly sum over the 16-lane group (masks 1,2,4,8 stay within group)
__device__ __forceinline__ float red16(float v) {
    v += __shfl_xor(v, 1);
    v += __shfl_xor(v, 2);
    v += __shfl_xor(v, 4);
    v += __shfl_xor(v, 8);
    return v;
}

__global__ __launch_bounds__(256) void ultragcn_main(
    const int*   __restrict__ user,
    const int*   __restrict__ pos,
    const int*   __restrict__ neg,
    const float* __restrict__ pos_beta,
    const float* __restrict__ neg_beta,
    const float* __restrict__ weights,
    const int*   __restrict__ neighbor,
    const float* __restrict__ embs,
    float*       __restrict__ partial)
{
    const int tid  = threadIdx.x;
    const int wave = tid >> 6;       // 0..3
    const int lane = tid & 63;
    const int i    = blockIdx.x * 4 + wave;   // batch element (BATCH = 4096*4 exact)

    const int g  = lane >> 4;        // group 0..3 within wave
    const int gl = lane & 15;        // lane within group (one float4 of the 64-dim row)
    const unsigned goff = (unsigned)(gl << 4);   // byte offset of this lane's float4 in a row

    const int u = user[i];
    const int p = pos[i];
    const int n = neg[i];

    const char* embsb = (const char*)embs;   // rows are 256 B; table 38.4 MB -> u32 offsets

    const float4 u4 = *(const float4*)(embsb + (unsigned)u * 256u + goff);
    const float4 p4 = *(const float4*)(embsb + (unsigned)p * 256u + goff);
    const float4 n4 = *(const float4*)(embsb + (unsigned)n * 256u + goff);

    const int item = p - USER_NUM;

    // preload neighbor ids + weights into lanes 0..49 (lanes >= 50 hold {0, 0.0f})
    int   nbv = 0;
    float wv  = 0.0f;
    if (lane < KNB) {
        nbv = neighbor[item * KNB + lane];
        wv  = weights[item * KNB + lane];
    }

    // Batch ALL neighbor gathers up front into registers: 13 independent
    // global_load_dwordx4 in flight per wave (L3-latency hiding), no trans
    // ops between them. Group g handles k = 4*t + g; k>=50 broadcasts lanes
    // 50/51 -> {row 0, weight 0} = harmless dummy.
    float4 e[13];
#pragma unroll
    for (int t = 0; t < 13; ++t) {
        const int nb = __shfl(nbv, 4 * t + g);
        e[t] = *(const float4*)(embsb + (unsigned)nb * 256u + goff);
    }
    float wk[13];
#pragma unroll
    for (int t = 0; t < 13; ++t) {
        wk[t] = __shfl(wv, 4 * t + g);
    }

    // redundant across groups but SIMD-free
    const float pos_logit = red16(dot4(u4, p4));
    const float neg_logit = red16(dot4(u4, n4));

    float li = 0.0f;
#pragma unroll
    for (int t = 0; t < 13; ++t) {
        const float d = red16(dot4(u4, e[t]));
        li += -log_sigmoid(d) * wk[t];
    }
    // each group's 16 lanes hold the group's partial; sum the 4 groups
    li += __shfl_xor(li, 16);
    li += __shfl_xor(li, 32);

    // LO + LC folded: -(1+pb)*ls(pos) - (1+nb)*ls(-neg)
    const float pb = pos_beta[i];
    const float nb = neg_beta[i];
    const float contrib = 2.5f * li
                        - (1.0f + pb) * log_sigmoid(pos_logit)
                        - (1.0f + nb) * log_sigmoid(-neg_logit);

    // block reduction across the 4 waves (all lanes of a wave hold contrib)
    __shared__ float s[4];
    if (lane == 0) s[wave] = contrib;
    __syncthreads();
    if (tid == 0) {
        partial[blockIdx.x] = s[0] + s[1] + s[2] + s[3];
    }
}

__global__ __launch_bounds__(256) void ultragcn_reduce(
    const float* __restrict__ partial, float* __restrict__ out, int n)
{
    const int tid  = threadIdx.x;
    const int lane = tid & 63;
    const int wave = tid >> 6;

    // n = 4096 = 256 threads * 4 float4
    const float4* p4 = (const float4*)partial;
    float s = 0.0f;
#pragma unroll
    for (int r = 0; r < 4; ++r) {
        float4 v = p4[r * 256 + tid];
        s += (v.x + v.y) + (v.z + v.w);
    }

    s += __shfl_xor(s, 1);
    s += __shfl_xor(s, 2);
    s += __shfl_xor(s, 4);
    s += __shfl_xor(s, 8);
    s += __shfl_xor(s, 16);
    s += __shfl_xor(s, 32);

    __shared__ float ws[4];
    if (lane == 0) ws[wave] = s;
    __syncthreads();
    if (tid == 0) out[0] = ws[0] + ws[1] + ws[2] + ws[3];
}

extern "C" void kernel_launch(void* const* d_in, const int* in_sizes, int n_in,
                              void* d_out, int out_size, void* d_ws, size_t ws_size,
                              hipStream_t stream)
{
    const int*   user     = (const int*)  d_in[0];
    const int*   pos      = (const int*)  d_in[1];
    const int*   neg      = (const int*)  d_in[2];
    const float* pos_beta = (const float*)d_in[3];
    const float* neg_beta = (const float*)d_in[4];
    const float* weights  = (const float*)d_in[5];
    const int*   neighbor = (const int*)  d_in[6];
    const float* embs     = (const float*)d_in[7];

    float* out     = (float*)d_out;
    float* partial = (float*)d_ws;       // 4096 floats = 16 KB scratch

    const int nblocks = BATCH / 4;       // 4096
    ultragcn_main<<<nblocks, 256, 0, stream>>>(
        user, pos, neg, pos_beta, neg_beta, weights, neighbor, embs, partial);
    ultragcn_reduce<<<1, 256, 0, stream>>>(partial, out, nblocks);
}